// Round 1
// baseline (74.228 us; speedup 1.0000x reference)
//
#include <hip/hip_runtime.h>

#define IMG_H 512
#define IMG_W 512
#define NBATCH 64
#define NBINS 256
#define TW 64
#define TH 32
#define HALO_W (TW + 2)   // 66
#define HALO_H (TH + 2)   // 34

// Zero the 64x256 output histogram (d_out is poisoned with 0xAA).
__global__ __launch_bounds__(256) void zero_out_kernel(float* __restrict__ out) {
    int i = blockIdx.x * 256 + threadIdx.x;
    if (i < NBATCH * NBINS) out[i] = 0.0f;
}

// Per-tile: stage gray (with halo) in LDS, compute LBP codes, LDS histogram,
// flush to global via one float atomicAdd per bin per block.
__global__ __launch_bounds__(256) void lbp_hist_kernel(const float* __restrict__ x,
                                                       float* __restrict__ hist) {
    __shared__ float g[HALO_H][HALO_W];
    __shared__ unsigned int lh[NBINS];

    const int b   = blockIdx.z;
    const int tx0 = blockIdx.x * TW;
    const int ty0 = blockIdx.y * TH;
    const int tid = threadIdx.x;

    lh[tid] = 0u;

    const float* base = x + (size_t)b * 3 * IMG_H * IMG_W;

    // Cooperative halo'd grayscale load: 34*66 = 2244 elements, 256 threads.
    for (int i = tid; i < HALO_H * HALO_W; i += 256) {
        int r = i / HALO_W;
        int c = i - r * HALO_W;
        int gy = ty0 + r - 1;
        gy = gy < 0 ? 0 : (gy > IMG_H - 1 ? IMG_H - 1 : gy);
        int gx = tx0 + c - 1;
        gx = gx < 0 ? 0 : (gx > IMG_W - 1 ? IMG_W - 1 : gx);
        int idx = gy * IMG_W + gx;
        float rr = base[idx];
        float gg = base[IMG_H * IMG_W + idx];
        float bb = base[2 * IMG_H * IMG_W + idx];
        g[r][c] = 0.2989f * rr + 0.587f * gg + 0.114f * bb;
    }
    __syncthreads();

    // Each thread handles column c, rows r0, r0+4, ..., r0+28 of the tile.
    const int c  = tid & 63;
    const int r0 = tid >> 6;
    #pragma unroll
    for (int rr = 0; rr < TH; rr += 4) {
        const int r = r0 + rr;
        const float ctr = g[r + 1][c + 1];
        // OFFSETS = ((-1,-1),(-1,0),(-1,1),(0,1),(1,1),(1,0),(1,-1),(0,-1))
        unsigned code = 0u;
        code |= (g[r    ][c    ] >= ctr) ? 1u   : 0u;
        code |= (g[r    ][c + 1] >= ctr) ? 2u   : 0u;
        code |= (g[r    ][c + 2] >= ctr) ? 4u   : 0u;
        code |= (g[r + 1][c + 2] >= ctr) ? 8u   : 0u;
        code |= (g[r + 2][c + 2] >= ctr) ? 16u  : 0u;
        code |= (g[r + 2][c + 1] >= ctr) ? 32u  : 0u;
        code |= (g[r + 2][c    ] >= ctr) ? 64u  : 0u;
        code |= (g[r + 1][c    ] >= ctr) ? 128u : 0u;
        atomicAdd(&lh[code], 1u);
    }
    __syncthreads();

    float v = (float)lh[tid];
    if (v != 0.0f) atomicAdd(&hist[b * NBINS + tid], v);
}

// In-place L2 normalization of each image's 256-bin histogram.
__global__ __launch_bounds__(256) void normalize_kernel(float* __restrict__ out) {
    const int b = blockIdx.x;
    const int t = threadIdx.x;
    float v = out[b * NBINS + t];
    float ss = v * v;
    #pragma unroll
    for (int o = 32; o > 0; o >>= 1) ss += __shfl_down(ss, o, 64);
    __shared__ float wsum[4];
    if ((t & 63) == 0) wsum[t >> 6] = ss;
    __syncthreads();
    float tot = wsum[0] + wsum[1] + wsum[2] + wsum[3];
    out[b * NBINS + t] = v / (sqrtf(tot) + 1e-6f);
}

extern "C" void kernel_launch(void* const* d_in, const int* in_sizes, int n_in,
                              void* d_out, int out_size, void* d_ws, size_t ws_size,
                              hipStream_t stream) {
    const float* x = (const float*)d_in[0];
    float* out = (float*)d_out;

    zero_out_kernel<<<NBATCH, 256, 0, stream>>>(out);

    dim3 grid(IMG_W / TW, IMG_H / TH, NBATCH);   // 8 x 16 x 64 = 8192 blocks
    lbp_hist_kernel<<<grid, 256, 0, stream>>>(x, out);

    normalize_kernel<<<NBATCH, 256, 0, stream>>>(out);
}

// Round 2
// 72.214 us; speedup vs baseline: 1.0279x; 1.0279x over previous
//
#include <hip/hip_runtime.h>

#define IMG_H 512
#define IMG_W 512
#define PLANE (IMG_H * IMG_W)
#define NBATCH 64
#define NBINS 256
#define TW 64
#define TH 32
#define LROWS (TH + 2)   // 34 LDS rows
#define LSTRIDE 68       // floats per LDS row; 68%32=4 -> even bank spread, rows 16B-aligned
#define SLOT_R 64        // right halo col slot
#define SLOT_L 66        // left halo col slot

#define GRAY(rr, gg, bb) (0.2989f * (rr) + 0.587f * (gg) + 0.114f * (bb))

__global__ __launch_bounds__(256) void zero_out_kernel(float* __restrict__ out) {
    int i = blockIdx.x * 256 + threadIdx.x;
    if (i < NBATCH * NBINS) out[i] = 0.0f;
}

__global__ __launch_bounds__(256) void lbp_hist_kernel(const float* __restrict__ x,
                                                       float* __restrict__ hist) {
    __shared__ float g[LROWS][LSTRIDE];
    __shared__ unsigned int lh[NBINS];

    const int b   = blockIdx.z;
    const int tx0 = blockIdx.x * TW;
    const int ty0 = blockIdx.y * TH;
    const int tid = threadIdx.x;
    const int r   = tid >> 3;   // 0..31 tile row
    const int j   = tid & 7;    // 0..7 col group (8 px each)

    lh[tid] = 0u;

    const float* rP = x + (size_t)b * 3 * PLANE;
    const float* gP = rP + PLANE;
    const float* bP = rP + 2 * PLANE;

    // ---- stage an 8-wide grayscale run from global into LDS row `lr` ----
    #define STAGE8(gy, lr)                                                        \
    do {                                                                          \
        const int gx = tx0 + 8 * j;                                               \
        const float4* r4 = (const float4*)(rP + (size_t)(gy) * IMG_W + gx);       \
        const float4* g4 = (const float4*)(gP + (size_t)(gy) * IMG_W + gx);       \
        const float4* b4 = (const float4*)(bP + (size_t)(gy) * IMG_W + gx);       \
        float4 ra = r4[0], rb = r4[1];                                            \
        float4 ga = g4[0], gb = g4[1];                                            \
        float4 ba = b4[0], bb = b4[1];                                            \
        float4 o0, o1;                                                            \
        o0.x = GRAY(ra.x, ga.x, ba.x); o0.y = GRAY(ra.y, ga.y, ba.y);             \
        o0.z = GRAY(ra.z, ga.z, ba.z); o0.w = GRAY(ra.w, ga.w, ba.w);             \
        o1.x = GRAY(rb.x, gb.x, bb.x); o1.y = GRAY(rb.y, gb.y, bb.y);             \
        o1.z = GRAY(rb.z, gb.z, bb.z); o1.w = GRAY(rb.w, gb.w, bb.w);             \
        *(float4*)&g[(lr)][8 * j]     = o0;                                       \
        *(float4*)&g[(lr)][8 * j + 4] = o1;                                       \
    } while (0)

    // Interior rows: tile row r -> LDS row r+1
    STAGE8(ty0 + r, r + 1);

    // Halo work, one wave each to limit divergence
    if (r == 0) {                       // top halo row -> LDS row 0
        int gy = ty0 - 1; if (gy < 0) gy = 0;
        STAGE8(gy, 0);
    } else if (r == 8) {                // bottom halo row -> LDS row 33
        int gy = ty0 + TH; if (gy > IMG_H - 1) gy = IMG_H - 1;
        STAGE8(gy, LROWS - 1);
    } else if (r == 16) {               // left halo col -> slot 66
        int gx = tx0 - 1; if (gx < 0) gx = 0;
        for (int lr = j; lr < LROWS; lr += 8) {
            int gy = ty0 + lr - 1;
            gy = gy < 0 ? 0 : (gy > IMG_H - 1 ? IMG_H - 1 : gy);
            size_t idx = (size_t)gy * IMG_W + gx;
            g[lr][SLOT_L] = GRAY(rP[idx], gP[idx], bP[idx]);
        }
    } else if (r == 24) {               // right halo col -> slot 64
        int gx = tx0 + TW; if (gx > IMG_W - 1) gx = IMG_W - 1;
        for (int lr = j; lr < LROWS; lr += 8) {
            int gy = ty0 + lr - 1;
            gy = gy < 0 ? 0 : (gy > IMG_H - 1 ? IMG_H - 1 : gy);
            size_t idx = (size_t)gy * IMG_W + gx;
            g[lr][SLOT_R] = GRAY(rP[idx], gP[idx], bP[idx]);
        }
    }
    #undef STAGE8

    __syncthreads();

    // ---- compute: thread (r,j) -> pixels (r, 8j..8j+7); 3-row register window ----
    // arr[0]=left neighbor (col 8j-1), arr[1..8]=cols 8j..8j+7, arr[9]=right (col 8j+8)
    float t_[10], m_[10], b_[10];
    #define LOADROW(arr, lr)                                                      \
    do {                                                                          \
        float4 a = *(const float4*)&g[(lr)][8 * j];                               \
        float4 c = *(const float4*)&g[(lr)][8 * j + 4];                           \
        arr[1] = a.x; arr[2] = a.y; arr[3] = a.z; arr[4] = a.w;                   \
        arr[5] = c.x; arr[6] = c.y; arr[7] = c.z; arr[8] = c.w;                   \
        arr[0] = g[(lr)][j > 0 ? 8 * j - 1 : SLOT_L];                             \
        arr[9] = g[(lr)][j < 7 ? 8 * j + 8 : SLOT_R];                             \
    } while (0)

    LOADROW(t_, r);
    LOADROW(m_, r + 1);
    LOADROW(b_, r + 2);
    #undef LOADROW

    #pragma unroll
    for (int c = 0; c < 8; ++c) {
        const float ctr = m_[c + 1];
        // OFFSETS = ((-1,-1),(-1,0),(-1,1),(0,1),(1,1),(1,0),(1,-1),(0,-1))
        unsigned code = 0u;
        code |= (t_[c    ] >= ctr) ? 1u   : 0u;
        code |= (t_[c + 1] >= ctr) ? 2u   : 0u;
        code |= (t_[c + 2] >= ctr) ? 4u   : 0u;
        code |= (m_[c + 2] >= ctr) ? 8u   : 0u;
        code |= (b_[c + 2] >= ctr) ? 16u  : 0u;
        code |= (b_[c + 1] >= ctr) ? 32u  : 0u;
        code |= (b_[c    ] >= ctr) ? 64u  : 0u;
        code |= (m_[c    ] >= ctr) ? 128u : 0u;
        atomicAdd(&lh[code], 1u);
    }

    __syncthreads();

    float v = (float)lh[tid];
    if (v != 0.0f) atomicAdd(&hist[b * NBINS + tid], v);
}

__global__ __launch_bounds__(256) void normalize_kernel(float* __restrict__ out) {
    const int b = blockIdx.x;
    const int t = threadIdx.x;
    float v = out[b * NBINS + t];
    float ss = v * v;
    #pragma unroll
    for (int o = 32; o > 0; o >>= 1) ss += __shfl_down(ss, o, 64);
    __shared__ float wsum[4];
    if ((t & 63) == 0) wsum[t >> 6] = ss;
    __syncthreads();
    float tot = wsum[0] + wsum[1] + wsum[2] + wsum[3];
    out[b * NBINS + t] = v / (sqrtf(tot) + 1e-6f);
}

extern "C" void kernel_launch(void* const* d_in, const int* in_sizes, int n_in,
                              void* d_out, int out_size, void* d_ws, size_t ws_size,
                              hipStream_t stream) {
    const float* x = (const float*)d_in[0];
    float* out = (float*)d_out;

    zero_out_kernel<<<NBATCH, 256, 0, stream>>>(out);

    dim3 grid(IMG_W / TW, IMG_H / TH, NBATCH);   // 8 x 16 x 64 = 8192 blocks
    lbp_hist_kernel<<<grid, 256, 0, stream>>>(x, out);

    normalize_kernel<<<NBATCH, 256, 0, stream>>>(out);
}

// Round 3
// 38.728 us; speedup vs baseline: 1.9166x; 1.8646x over previous
//
#include <hip/hip_runtime.h>

#define IMG_H 512
#define IMG_W 512
#define PLANE (IMG_H * IMG_W)
#define NBATCH 64
#define NBINS 256
#define TSTRIP 16                               // rows per wave-strip
#define WAVES_PER_BLOCK 4
#define STRIPS_PER_IMG (IMG_H / TSTRIP)         // 32
#define BLOCKS_PER_IMG (STRIPS_PER_IMG / WAVES_PER_BLOCK)  // 8

#define GRAY(rr, gg, bb) (0.2989f * (rr) + 0.587f * (gg) + 0.114f * (bb))

// One wave walks a 16-row x 512-wide strip with a 3-row register ring.
// Lane j owns pixels [8j, 8j+8). Horizontal neighbors via shfl. No LDS staging.
__global__ __launch_bounds__(256) void lbp_strip_kernel(const float* __restrict__ x,
                                                        float* __restrict__ ws) {
    __shared__ unsigned int lh[NBINS];
    const int tid = threadIdx.x;
    lh[tid] = 0u;                                // 256 threads == 256 bins
    __syncthreads();

    const int b     = blockIdx.y;
    const int wav   = tid >> 6;                  // 0..3
    const int lane  = tid & 63;
    const int strip = blockIdx.x * WAVES_PER_BLOCK + wav;   // 0..31
    const int y0    = strip * TSTRIP;

    const float* rP = x + (size_t)b * 3 * PLANE;
    const float* gP = rP + PLANE;
    const float* bP = rP + 2 * PLANE;
    const int    cx = 8 * lane;                  // lane's first column

    // arr[0]=left edge (col cx-1), arr[1..8]=cols cx..cx+7, arr[9]=right edge (col cx+8)
    float t_[10], m_[10], b_[10];

    #define LOADGRAY(arr, gy_)                                                     \
    do {                                                                           \
        int gy = (gy_);                                                            \
        gy = gy < 0 ? 0 : (gy > IMG_H - 1 ? IMG_H - 1 : gy);                       \
        size_t off = (size_t)gy * IMG_W + cx;                                      \
        float4 ra = *(const float4*)(rP + off), rb = *(const float4*)(rP + off + 4);\
        float4 ga = *(const float4*)(gP + off), gb = *(const float4*)(gP + off + 4);\
        float4 ba = *(const float4*)(bP + off), bb = *(const float4*)(bP + off + 4);\
        arr[1] = GRAY(ra.x, ga.x, ba.x); arr[2] = GRAY(ra.y, ga.y, ba.y);          \
        arr[3] = GRAY(ra.z, ga.z, ba.z); arr[4] = GRAY(ra.w, ga.w, ba.w);          \
        arr[5] = GRAY(rb.x, gb.x, bb.x); arr[6] = GRAY(rb.y, gb.y, bb.y);          \
        arr[7] = GRAY(rb.z, gb.z, bb.z); arr[8] = GRAY(rb.w, gb.w, bb.w);          \
        float lft = __shfl_up(arr[8], 1, 64);                                      \
        float rgt = __shfl_down(arr[1], 1, 64);                                    \
        arr[0] = (lane == 0)  ? arr[1] : lft;                                      \
        arr[9] = (lane == 63) ? arr[8] : rgt;                                      \
    } while (0)

    LOADGRAY(t_, y0 - 1);
    LOADGRAY(m_, y0);

    #pragma unroll 4
    for (int i = 0; i < TSTRIP; ++i) {
        LOADGRAY(b_, y0 + 1 + i);
        #pragma unroll
        for (int p = 0; p < 8; ++p) {
            const float ctr = m_[p + 1];
            // OFFSETS = ((-1,-1),(-1,0),(-1,1),(0,1),(1,1),(1,0),(1,-1),(0,-1))
            unsigned code = 0u;
            code |= (t_[p    ] >= ctr) ? 1u   : 0u;
            code |= (t_[p + 1] >= ctr) ? 2u   : 0u;
            code |= (t_[p + 2] >= ctr) ? 4u   : 0u;
            code |= (m_[p + 2] >= ctr) ? 8u   : 0u;
            code |= (b_[p + 2] >= ctr) ? 16u  : 0u;
            code |= (b_[p + 1] >= ctr) ? 32u  : 0u;
            code |= (b_[p    ] >= ctr) ? 64u  : 0u;
            code |= (m_[p    ] >= ctr) ? 128u : 0u;
            atomicAdd(&lh[code], 1u);
        }
        #pragma unroll
        for (int k = 0; k < 10; ++k) { t_[k] = m_[k]; m_[k] = b_[k]; }
    }
    #undef LOADGRAY

    __syncthreads();
    // one partial histogram per block, no global atomics
    ws[((size_t)b * BLOCKS_PER_IMG + blockIdx.x) * NBINS + tid] = (float)lh[tid];
}

// Sum the 8 partials per image, L2-normalize, write output.
__global__ __launch_bounds__(256) void finalize_kernel(const float* __restrict__ ws,
                                                       float* __restrict__ out) {
    const int b = blockIdx.x;
    const int t = threadIdx.x;
    float s = 0.0f;
    #pragma unroll
    for (int k = 0; k < BLOCKS_PER_IMG; ++k)
        s += ws[((size_t)b * BLOCKS_PER_IMG + k) * NBINS + t];
    float ss = s * s;
    #pragma unroll
    for (int o = 32; o > 0; o >>= 1) ss += __shfl_down(ss, o, 64);
    __shared__ float wsum[4];
    if ((t & 63) == 0) wsum[t >> 6] = ss;
    __syncthreads();
    float tot = wsum[0] + wsum[1] + wsum[2] + wsum[3];
    out[b * NBINS + t] = s / (sqrtf(tot) + 1e-6f);
}

extern "C" void kernel_launch(void* const* d_in, const int* in_sizes, int n_in,
                              void* d_out, int out_size, void* d_ws, size_t ws_size,
                              hipStream_t stream) {
    const float* x = (const float*)d_in[0];
    float* out = (float*)d_out;
    float* ws  = (float*)d_ws;   // 64 * 8 * 256 floats = 512 KB partial histograms

    dim3 grid(BLOCKS_PER_IMG, NBATCH);           // 8 x 64 = 512 blocks, 4 wave-strips each
    lbp_strip_kernel<<<grid, 256, 0, stream>>>(x, ws);

    finalize_kernel<<<NBATCH, 256, 0, stream>>>(ws, out);
}

// Round 4
// 37.880 us; speedup vs baseline: 1.9595x; 1.0224x over previous
//
#include <hip/hip_runtime.h>

#define IMG_H 512
#define IMG_W 512
#define PLANE (IMG_H * IMG_W)
#define NBATCH 64
#define NBINS 256
#define TSTRIP 16                               // rows per wave-strip
#define WAVES_PER_BLOCK 4
#define STRIPS_PER_IMG (IMG_H / TSTRIP)         // 32
#define BLOCKS_PER_IMG (STRIPS_PER_IMG / WAVES_PER_BLOCK)  // 8
#define NBLOCKS (BLOCKS_PER_IMG * NBATCH)       // 512

#define GRAY(rr, gg, bb) (0.2989f * (rr) + 0.587f * (gg) + 0.114f * (bb))

// One wave walks a 16-row x 512-wide strip with a 3-row register ring.
// Odd strips walk bottom-up (snake) so boundary rows are re-read co-temporally
// by the neighboring strip -> L1/L2 hit instead of HBM re-fetch.
// 1-D grid with XCD swizzle: all 8 blocks of an image share one XCD's L2.
__global__ __launch_bounds__(256) void lbp_strip_kernel(const float* __restrict__ x,
                                                        float* __restrict__ ws) {
    __shared__ unsigned int lh[NBINS];
    const int tid = threadIdx.x;
    lh[tid] = 0u;                                // 256 threads == 256 bins
    __syncthreads();

    // XCD swizzle: XCD = blockIdx.x % 8 (round-robin). Map so image = sid>>3
    // groups 8 blocks (one image) onto one XCD.
    const int lin = blockIdx.x;                  // 0..511
    const int sid = (lin & 7) * (NBLOCKS / 8) + (lin >> 3);
    const int b   = sid >> 3;                    // image 0..63
    const int bg  = sid & 7;                     // strip-group 0..7

    const int wav   = tid >> 6;                  // 0..3
    const int lane  = tid & 63;
    const int strip = bg * WAVES_PER_BLOCK + wav;   // 0..31
    const int y0    = strip * TSTRIP;

    const float* rP = x + (size_t)b * 3 * PLANE;
    const float* gP = rP + PLANE;
    const float* bP = rP + 2 * PLANE;
    const int    cx = 8 * lane;                  // lane's first column

    // arr[0]=left edge (col cx-1), arr[1..8]=cols cx..cx+7, arr[9]=right edge (col cx+8)
    float t_[10], m_[10], b_[10];

    #define LOADGRAY(arr, gy_)                                                     \
    do {                                                                           \
        int gy = (gy_);                                                            \
        gy = gy < 0 ? 0 : (gy > IMG_H - 1 ? IMG_H - 1 : gy);                       \
        size_t off = (size_t)gy * IMG_W + cx;                                      \
        float4 ra = *(const float4*)(rP + off), rb = *(const float4*)(rP + off + 4);\
        float4 ga = *(const float4*)(gP + off), gb = *(const float4*)(gP + off + 4);\
        float4 ba = *(const float4*)(bP + off), bb = *(const float4*)(bP + off + 4);\
        arr[1] = GRAY(ra.x, ga.x, ba.x); arr[2] = GRAY(ra.y, ga.y, ba.y);          \
        arr[3] = GRAY(ra.z, ga.z, ba.z); arr[4] = GRAY(ra.w, ga.w, ba.w);          \
        arr[5] = GRAY(rb.x, gb.x, bb.x); arr[6] = GRAY(rb.y, gb.y, bb.y);          \
        arr[7] = GRAY(rb.z, gb.z, bb.z); arr[8] = GRAY(rb.w, gb.w, bb.w);          \
        float lft = __shfl_up(arr[8], 1, 64);                                      \
        float rgt = __shfl_down(arr[1], 1, 64);                                    \
        arr[0] = (lane == 0)  ? arr[1] : lft;                                      \
        arr[9] = (lane == 63) ? arr[8] : rgt;                                      \
    } while (0)

    // OFFSETS = ((-1,-1),(-1,0),(-1,1),(0,1),(1,1),(1,0),(1,-1),(0,-1))
    #define COMPUTE8()                                                             \
    do {                                                                           \
        _Pragma("unroll")                                                          \
        for (int p = 0; p < 8; ++p) {                                              \
            const float ctr = m_[p + 1];                                           \
            unsigned code = 0u;                                                    \
            code |= (t_[p    ] >= ctr) ? 1u   : 0u;                                \
            code |= (t_[p + 1] >= ctr) ? 2u   : 0u;                                \
            code |= (t_[p + 2] >= ctr) ? 4u   : 0u;                                \
            code |= (m_[p + 2] >= ctr) ? 8u   : 0u;                                \
            code |= (b_[p + 2] >= ctr) ? 16u  : 0u;                                \
            code |= (b_[p + 1] >= ctr) ? 32u  : 0u;                                \
            code |= (b_[p    ] >= ctr) ? 64u  : 0u;                                \
            code |= (m_[p    ] >= ctr) ? 128u : 0u;                                \
            atomicAdd(&lh[code], 1u);                                              \
        }                                                                          \
    } while (0)

    if ((strip & 1) == 0) {
        // walk top -> bottom
        LOADGRAY(t_, y0 - 1);
        LOADGRAY(m_, y0);
        #pragma unroll 4
        for (int i = 0; i < TSTRIP; ++i) {
            LOADGRAY(b_, y0 + 1 + i);
            COMPUTE8();
            #pragma unroll
            for (int k = 0; k < 10; ++k) { t_[k] = m_[k]; m_[k] = b_[k]; }
        }
    } else {
        // walk bottom -> top
        LOADGRAY(b_, y0 + TSTRIP);
        LOADGRAY(m_, y0 + TSTRIP - 1);
        #pragma unroll 4
        for (int i = 0; i < TSTRIP; ++i) {
            LOADGRAY(t_, y0 + TSTRIP - 2 - i);
            COMPUTE8();
            #pragma unroll
            for (int k = 0; k < 10; ++k) { b_[k] = m_[k]; m_[k] = t_[k]; }
        }
    }
    #undef LOADGRAY
    #undef COMPUTE8

    __syncthreads();
    // one partial histogram per block, no global atomics
    ws[((size_t)b * BLOCKS_PER_IMG + bg) * NBINS + tid] = (float)lh[tid];
}

// Sum the 8 partials per image, L2-normalize, write output.
__global__ __launch_bounds__(256) void finalize_kernel(const float* __restrict__ ws,
                                                       float* __restrict__ out) {
    const int b = blockIdx.x;
    const int t = threadIdx.x;
    float s = 0.0f;
    #pragma unroll
    for (int k = 0; k < BLOCKS_PER_IMG; ++k)
        s += ws[((size_t)b * BLOCKS_PER_IMG + k) * NBINS + t];
    float ss = s * s;
    #pragma unroll
    for (int o = 32; o > 0; o >>= 1) ss += __shfl_down(ss, o, 64);
    __shared__ float wsum[4];
    if ((t & 63) == 0) wsum[t >> 6] = ss;
    __syncthreads();
    float tot = wsum[0] + wsum[1] + wsum[2] + wsum[3];
    out[b * NBINS + t] = s / (sqrtf(tot) + 1e-6f);
}

extern "C" void kernel_launch(void* const* d_in, const int* in_sizes, int n_in,
                              void* d_out, int out_size, void* d_ws, size_t ws_size,
                              hipStream_t stream) {
    const float* x = (const float*)d_in[0];
    float* out = (float*)d_out;
    float* ws  = (float*)d_ws;   // 64 * 8 * 256 floats = 512 KB partial histograms

    lbp_strip_kernel<<<NBLOCKS, 256, 0, stream>>>(x, ws);
    finalize_kernel<<<NBATCH, 256, 0, stream>>>(ws, out);
}